// Round 14
// baseline (143.159 us; speedup 1.0000x reference)
//
#include <hip/hip_runtime.h>

// MorphoMLP: y = relu(maxplus(relu(maxplus(x,W1)), W2)), fp32.
// B=512, IN=512, HID=1024, OUT=512.
// R17: R13 base (91.2us best) + ONE mechanism: T14 async-split double-buffer
//      in the morpho k-loop (load next phase to regs BEFORE computing current,
//      LDS-write after the barrier). R15's regression was the nt stores
//      (LLC-no-allocate pushed boundary partials to HBM) — reverted; cached
//      loads/stores everywhere, exactly as R13.
//   - M1: NT, JTILE=64, KPER=128 (2 phases, dbuf), z=4, grid(16,8,4)=512.
//   - combineH: hp(8MB) -> A2(2MB), relu. 512 blocks.
//   - M2: NT, JTILE=64, KPER=128 (2 phases, dbuf), z=8, grid(8,8,8)=512.
//   - combineY: 8 slices -> out. 256 blocks.
//   - LDS 64KB/block (2 x 2 x 16KB), still 2 blocks/CU. VGPR ~88.
//   - acc init 0 folds relu exactly; max order-exact -> absmax 0.
// ws: hp 8MB | A2 2MB | yp 8MB = 18MB

#define WS_HP   0                            // [4][512][1024]  L1 partials [z][b][j]
#define WS_A2   (4 * 512 * 1024)             // [512][1024]     relu(h) [b][k2]
#define WS_YP   (WS_A2 + 512 * 1024)         // [8][512][512]   L2 partials [z][b][o]

typedef float f32x2 __attribute__((ext_vector_type(2)));

__device__ __forceinline__ float4 fmax4(float4 a, float4 b) {
    return make_float4(fmaxf(a.x, b.x), fmaxf(a.y, b.y),
                       fmaxf(a.z, b.z), fmaxf(a.w, b.w));
}

// ---------------------------------------------------------------------------
// NT max-plus tile kernel, T14 double-buffered staging (cached stores).
// A: [*][AROWF4*4] row-major (b rows); W: [*][WROWF4*4] row-major (j rows).
// Block tile: 64 j x 64 b x 128 k (2 phases of 64k, dbuf).
// 256 thr: tx=t>>4 -> 4 b-rows; ty=t&15 -> 4 j-rows.
// LDS [row][16 f4], swizzle col^=(row>>2)&7 both sides (R13-verbatim).
// Stores partial P[bz][b][j] (f4 over j, coalesced).
template <int JTILE, int AROWF4, int WROWF4, int OUTW>
__global__ __launch_bounds__(256, 2) void morphoNT5(const float* __restrict__ A,
                                                    const float* __restrict__ Wm,
                                                    float* __restrict__ P) {
    constexpr int JROWS = JTILE / 16;          // 4
    __shared__ float lA[2][64 * 64];           // [buf][b-row][64k] 16KB each
    __shared__ float lW[2][JTILE * 64];        // [buf][j-row][64k] 16KB each
    const int t  = threadIdx.x;
    const int tx = t >> 4;
    const int ty = t & 15;
    const int j0 = blockIdx.x * JTILE;
    const int b0 = blockIdx.y * 64;
    const int kbase = blockIdx.z * 32;         // KPER=128 -> 32 f4 per row

    const float4* A4 = (const float4*)A;
    const float4* W4 = (const float4*)Wm;

    float acc[4][JROWS];
#pragma unroll
    for (int bi = 0; bi < 4; bi++)
#pragma unroll
        for (int jr = 0; jr < JROWS; jr++) acc[bi][jr] = 0.0f;

    const int swA = tx & 7;
    const int swW = ty & 7;

    float4 av[4], wv[4];

    // ---- load + write phase 0 ----
#pragma unroll
    for (int s = 0; s < 4; s++) {
        const int q = t + 256 * s, r = q >> 4, c = q & 15;
        av[s] = A4[(size_t)(b0 + r) * AROWF4 + kbase + c];
        wv[s] = W4[(size_t)(j0 + r) * WROWF4 + kbase + c];
    }
#pragma unroll
    for (int s = 0; s < 4; s++) {
        const int q = t + 256 * s, r = q >> 4, c = q & 15;
        ((float4*)lA[0])[r * 16 + (c ^ ((r >> 2) & 7))] = av[s];
        ((float4*)lW[0])[r * 16 + (c ^ ((r >> 2) & 7))] = wv[s];
    }
    // ---- issue phase-1 loads; latency hides under phase-0 compute ----
#pragma unroll
    for (int s = 0; s < 4; s++) {
        const int q = t + 256 * s, r = q >> 4, c = q & 15;
        av[s] = A4[(size_t)(b0 + r) * AROWF4 + kbase + 16 + c];
        wv[s] = W4[(size_t)(j0 + r) * WROWF4 + kbase + 16 + c];
    }
    __syncthreads();

#pragma unroll
    for (int ph = 0; ph < 2; ph++) {
        const float4* pA  = ((const float4*)lA[ph]) + tx * 4 * 16;
        const float4* pWl = ((const float4*)lW[ph]) + ty * 4 * 16;

        // ---- k burst: 16 iters x 4k; pk_add + v_max3 (R13-verbatim) ----
#pragma unroll 4
        for (int c = 0; c < 16; c++) {
            const int cA = c ^ swA, cW = c ^ swW;
            float4 a[4];
#pragma unroll
            for (int bi = 0; bi < 4; bi++) a[bi] = pA[bi * 16 + cA];
            float4 w[JROWS];
#pragma unroll
            for (int ji = 0; ji < JROWS; ji++) w[ji] = pWl[ji * 16 + cW];
#pragma unroll
            for (int bi = 0; bi < 4; bi++) {
                const f32x2 alo = {a[bi].x, a[bi].y};
                const f32x2 ahi = {a[bi].z, a[bi].w};
#pragma unroll
                for (int jr = 0; jr < JROWS; jr++) {
                    const f32x2 s = alo + (f32x2){w[jr].x, w[jr].y};  // pk_add
                    const f32x2 u = ahi + (f32x2){w[jr].z, w[jr].w};  // pk_add
                    const float m = fmaxf(fmaxf(s.x, s.y), u.x);      // v_max3
                    acc[bi][jr]   = fmaxf(fmaxf(acc[bi][jr], m), u.y);// v_max3
                }
            }
        }

        if (ph == 0) {
            // write buf1 from regs (buf1 disjoint from buf0 readers)
#pragma unroll
            for (int s = 0; s < 4; s++) {
                const int q = t + 256 * s, r = q >> 4, c = q & 15;
                ((float4*)lA[1])[r * 16 + (c ^ ((r >> 2) & 7))] = av[s];
                ((float4*)lW[1])[r * 16 + (c ^ ((r >> 2) & 7))] = wv[s];
            }
            __syncthreads();
        }
    }

    // ---- store partial: P[bz][b][j], cached (stays in L2/L3 for consumer) ----
    float* Pp = P + (size_t)blockIdx.z * (512 * OUTW);
#pragma unroll
    for (int bi = 0; bi < 4; bi++) {
        float* row = Pp + (size_t)(b0 + tx * 4 + bi) * OUTW + j0 + ty * 4;
        *(float4*)(row) = make_float4(acc[bi][0], acc[bi][1], acc[bi][2], acc[bi][3]);
    }
}

// ---------------------------------------------------------------------------
// combineH: A2[b][k2] = relu(max_z hp[z][b][k2]). Coalesced f4, 4 slices.
__global__ __launch_bounds__(256) void combineH3(const float* __restrict__ hp,
                                                 float* __restrict__ A2) {
    const int i = blockIdx.x * 256 + threadIdx.x;
    const float4* p = (const float4*)hp;
    float4 m = p[i];
#pragma unroll
    for (int z = 1; z < 4; z++) m = fmax4(m, p[i + z * 131072]);  // 512K/4
    m = fmax4(m, make_float4(0.f, 0.f, 0.f, 0.f));
    ((float4*)A2)[i] = m;
}

// ---------------------------------------------------------------------------
// combineY: out[b][o] = max_z yp[z][b][o] (pre-relu'd). Coalesced, 8 slices.
__global__ __launch_bounds__(256) void combineY4(const float* __restrict__ yp,
                                                 float* __restrict__ out) {
    const int i = blockIdx.x * 256 + threadIdx.x;
    const float4* p = (const float4*)yp;
    float4 m = p[i];
#pragma unroll
    for (int z = 1; z < 8; z++) m = fmax4(m, p[i + z * 65536]);  // 256K/4
    ((float4*)out)[i] = m;
}

// ---------------------------------------------------------------------------
extern "C" void kernel_launch(void* const* d_in, const int* in_sizes, int n_in,
                              void* d_out, int out_size, void* d_ws, size_t ws_size,
                              hipStream_t stream) {
    (void)in_sizes; (void)n_in; (void)out_size; (void)ws_size;
    const float* x  = (const float*)d_in[0];   // [512][512]   b x k
    const float* W1 = (const float*)d_in[1];   // [1024][512]  j x k
    const float* W2 = (const float*)d_in[2];   // [512][1024]  o x k2
    float* ws  = (float*)d_ws;
    float* out = (float*)d_out;

    // 1) L1: hp[4][b][j]; grid 16(j) x 8(b) x 4(z) = 512 blocks, 64KB LDS.
    morphoNT5<64, 128, 128, 1024>
        <<<dim3(16, 8, 4), 256, 0, stream>>>(x, W1, ws + WS_HP);

    // 2) combine 4 slices + relu -> A2[b][k2] (2MB)
    combineH3<<<512, 256, 0, stream>>>(ws + WS_HP, ws + WS_A2);

    // 3) L2: yp[8][b][o]; grid 8(o) x 8(b) x 8(z) = 512 blocks, 64KB LDS.
    morphoNT5<64, 256, 256, 512>
        <<<dim3(8, 8, 8), 256, 0, stream>>>(ws + WS_A2, W2, ws + WS_YP);

    // 4) combine 8 slices -> out[b][o]
    combineY4<<<256, 256, 0, stream>>>(ws + WS_YP, out);
}